// Round 6
// baseline (257.964 us; speedup 1.0000x reference)
//
#include <hip/hip_runtime.h>
#include <hip/hip_bf16.h>

#define B_SZ 8192
#define D_SZ 1024   // elements; == bytes in fp8

typedef __attribute__((ext_vector_type(4))) float floatx4;
typedef __attribute__((ext_vector_type(8))) int   int8v;
typedef __attribute__((ext_vector_type(4))) int   int4v;

__device__ __forceinline__ void glds16(const void* g, void* l) {
    __builtin_amdgcn_global_load_lds(
        (const __attribute__((address_space(1))) void*)g,
        (__attribute__((address_space(3))) void*)l, 16, 0, 0);
}

// One wave per row (rows 0..8191 = img, 8192..16383 = txt). 4 rows/block.
// Also zero-inits the output accumulator (stream-ordered before GEMM atomics).
__global__ __launch_bounds__(256) void norm_cast_fp8(
    const float* __restrict__ img, const float* __restrict__ txt,
    unsigned char* __restrict__ imgQ, unsigned char* __restrict__ txtQ,
    float* __restrict__ out)
{
    if (blockIdx.x == 0 && threadIdx.x == 0) *out = 0.0f;

    const int lane = threadIdx.x & 63;
    int w = blockIdx.x * 4 + (threadIdx.x >> 6);
    const float* src; unsigned char* dst;
    if (w < B_SZ) { src = img + (size_t)w * D_SZ; dst = imgQ + (size_t)w * D_SZ; }
    else { w -= B_SZ; src = txt + (size_t)w * D_SZ; dst = txtQ + (size_t)w * D_SZ; }

    float4 v[4];
    float ss = 0.0f;
    #pragma unroll
    for (int i = 0; i < 4; ++i) {
        v[i] = ((const float4*)src)[lane + 64 * i];
        ss += v[i].x*v[i].x + v[i].y*v[i].y + v[i].z*v[i].z + v[i].w*v[i].w;
    }
    #pragma unroll
    for (int off = 1; off < 64; off <<= 1) ss += __shfl_xor(ss, off, 64);
    const float scale = 1.0f / fmaxf(sqrtf(ss), 1e-12f);

    #pragma unroll
    for (int i = 0; i < 4; ++i) {
        int packed = 0;
        packed = __builtin_amdgcn_cvt_pk_fp8_f32(v[i].x * scale, v[i].y * scale, packed, false);
        packed = __builtin_amdgcn_cvt_pk_fp8_f32(v[i].z * scale, v[i].w * scale, packed, true);
        ((int*)dst)[lane + 64 * i] = packed;
    }
}

// Fused MX-fp8 GEMM (A @ B^T) + SigLIP loss. 128x128 block tile, 4 waves 2x2,
// wave tile 64x64 (4x4 of 16x16x128 scaled-MFMA, scales = 1.0), 8 K-iters.
//
// B comes through LDS (single-buffered, R4 structure: B-frags pulled to regs,
// then barrier licenses the next tile's DMA which flies during the MFMAs).
// A-fragments are loaded DIRECTLY from global to VGPRs (lane l16 = row,
// quad = 32-byte K-chunk; two dwordx4 per fragment). A rows are L2/L3
// resident (16 MB total) and L1-shared by the two waves with the same wm;
// the loads issue before the MFMA phase and drain under it via vmcnt.
// LDS = 16.5 KB -> occupancy is VGPR-bound (~3 blocks/CU vs R4's ~2-3 with
// double the LDS-pipe pressure).
__global__ __launch_bounds__(256, 3) void siglip_gemm_loss_fp8(
    const unsigned char* __restrict__ A,   // imgQ [B,D] e4m3
    const unsigned char* __restrict__ Bt,  // txtQ [B,D] e4m3
    const float* __restrict__ tp, const float* __restrict__ bp,
    float* __restrict__ out)
{
    __shared__ __align__(16) unsigned char Bs[2][128 * 64];  // [lo/hi] 16 KB

    const int tid  = threadIdx.x;
    const int lane = tid & 63;
    const int wave = tid >> 6;
    const int wm = wave & 1, wn = wave >> 1;
    const int bi = blockIdx.x * 128;
    const int bj = blockIdx.y * 128;
    const int quad = lane >> 4;   // 0..3 -> 32-byte K-chunk
    const int l16  = lane & 15;

    floatx4 acc[4][4];
    #pragma unroll
    for (int i = 0; i < 4; ++i)
        #pragma unroll
        for (int j = 0; j < 4; ++j)
            acc[i][j] = (floatx4){0.f, 0.f, 0.f, 0.f};

    // B staging: 512 slots per half-array; slot s -> row = s>>2, phys p = s&3,
    // global granule g = p ^ ((row>>1)&3)  (R2's conflict-minimal geometry).
    auto stage_b = [&](int k0) {
        #pragma unroll
        for (int it = 0; it < 2; ++it) {
            int s = tid + it * 256;
            int row = s >> 2, p = s & 3;
            int g = p ^ ((row >> 1) & 3);
            const unsigned char* gb = Bt + ((size_t)(bj + row) * D_SZ + k0 + g * 16);
            glds16(gb,      Bs[0] + s * 16);
            glds16(gb + 64, Bs[1] + s * 16);
        }
    };

    // B-fragment read geometry (proven R2/R4): array = quad>>1, granule pair
    // (quad&1)*2 ^ sw, sw = (l16>>1)&3.
    const int sw   = (l16 >> 1) & 3;
    const int hsel = quad >> 1;
    const int p0   = ((quad & 1) * 2) ^ sw;
    const int p1   = p0 ^ 1;

    // A direct-load base: row (bi + mt*16 + l16), K-bytes quad*32 .. +31.
    const unsigned char* a_lane = A + (size_t)(bi + l16) * D_SZ + quad * 32;

    stage_b(0);

    for (int kk = 0; kk < D_SZ / 128; ++kk) {
        __syncthreads();   // (A) staging DMA from previous issue visible

        int8v bfr[4];
        #pragma unroll
        for (int nt = 0; nt < 4; ++nt) {
            int r = wn * 64 + nt * 16 + l16;
            int4v lo = *(const int4v*)(Bs[hsel] + r * 64 + p0 * 16);
            int4v hi = *(const int4v*)(Bs[hsel] + r * 64 + p1 * 16);
            bfr[nt][0]=lo[0]; bfr[nt][1]=lo[1]; bfr[nt][2]=lo[2]; bfr[nt][3]=lo[3];
            bfr[nt][4]=hi[0]; bfr[nt][5]=hi[1]; bfr[nt][6]=hi[2]; bfr[nt][7]=hi[3];
        }
        __syncthreads();   // (B) all waves consumed Bs -> overwrite licensed

        if (kk + 1 < D_SZ / 128)
            stage_b((kk + 1) * 128);   // DMA flies during loads+MFMAs below

        // A-fragments straight from global (L1/L2): issue all 8 loads, then
        // MFMA; compiler interleaves via vmcnt.
        const unsigned char* ak = a_lane + (size_t)(wm * 64) * D_SZ + kk * 128;
        int8v af[4];
        #pragma unroll
        for (int mt = 0; mt < 4; ++mt) {
            const unsigned char* ap = ak + (size_t)(mt * 16) * D_SZ;
            int4v lo = *(const int4v*)(ap);
            int4v hi = *(const int4v*)(ap + 16);
            af[mt][0]=lo[0]; af[mt][1]=lo[1]; af[mt][2]=lo[2]; af[mt][3]=lo[3];
            af[mt][4]=hi[0]; af[mt][5]=hi[1]; af[mt][6]=hi[2]; af[mt][7]=hi[3];
        }

        #pragma unroll
        for (int mt = 0; mt < 4; ++mt)
            #pragma unroll
            for (int nt = 0; nt < 4; ++nt)
                acc[mt][nt] = __builtin_amdgcn_mfma_scale_f32_16x16x128_f8f6f4(
                    af[mt], bfr[nt], acc[mt][nt],
                    0, 0,          // cbsz=fp8, blgp=fp8
                    0, 127,        // scale A: E8M0 127 = 1.0
                    0, 127);       // scale B
    }

    // Epilogue: softplus(-label*logit) with hw exp/log, reduce.
    const float t    = fminf(__expf(tp[0]), 100.0f);
    const float bias = bp[0];
    float lsum = 0.0f;
    #pragma unroll
    for (int mt = 0; mt < 4; ++mt) {
        #pragma unroll
        for (int nt = 0; nt < 4; ++nt) {
            const int jj = bj + wn * 64 + nt * 16 + l16;              // C/D col
            #pragma unroll
            for (int r = 0; r < 4; ++r) {
                const int ii = bi + wm * 64 + mt * 16 + quad * 4 + r; // C/D row
                float logit = fmaf(acc[mt][nt][r], t, bias);
                float z = (ii == jj) ? logit : -logit;
                float e = __expf(-fabsf(z));
                lsum += fmaxf(-z, 0.0f) + __logf(1.0f + e);
            }
        }
    }
    #pragma unroll
    for (int off = 32; off > 0; off >>= 1) lsum += __shfl_down(lsum, off, 64);

    __shared__ float red[4];
    if (lane == 0) red[wave] = lsum;
    __syncthreads();
    if (tid == 0)
        atomicAdd(out, (red[0] + red[1] + red[2] + red[3]) * (1.0f / (float)B_SZ));
}

extern "C" void kernel_launch(void* const* d_in, const int* in_sizes, int n_in,
                              void* d_out, int out_size, void* d_ws, size_t ws_size,
                              hipStream_t stream) {
    const float* img = (const float*)d_in[0];
    const float* txt = (const float*)d_in[1];
    const float* tp  = (const float*)d_in[2];
    const float* bp  = (const float*)d_in[3];
    float* out = (float*)d_out;

    unsigned char* imgQ = (unsigned char*)d_ws;                   // 8 MB
    unsigned char* txtQ = imgQ + (size_t)B_SZ * D_SZ;             // 8 MB

    norm_cast_fp8<<<(2 * B_SZ) / 4, 256, 0, stream>>>(img, txt, imgQ, txtQ, out);
    dim3 grid(B_SZ / 128, B_SZ / 128);
    siglip_gemm_loss_fp8<<<grid, 256, 0, stream>>>(imgQ, txtQ, tp, bp, out);
}

// Round 7
// 192.472 us; speedup vs baseline: 1.3403x; 1.3403x over previous
//
#include <hip/hip_runtime.h>
#include <hip/hip_bf16.h>

#define B_SZ 8192
#define D_SZ 1024   // elements; == bytes in fp8

typedef __attribute__((ext_vector_type(4))) float floatx4;
typedef __attribute__((ext_vector_type(8))) int   int8v;
typedef __attribute__((ext_vector_type(4))) int   int4v;

__device__ __forceinline__ void glds16(const void* g, void* l) {
    __builtin_amdgcn_global_load_lds(
        (const __attribute__((address_space(1))) void*)g,
        (__attribute__((address_space(3))) void*)l, 16, 0, 0);
}

// One wave per row (rows 0..8191 = img, 8192..16383 = txt). 4 rows/block.
// Also zero-inits the output accumulator (stream-ordered before GEMM atomics).
__global__ __launch_bounds__(256) void norm_cast_fp8(
    const float* __restrict__ img, const float* __restrict__ txt,
    unsigned char* __restrict__ imgQ, unsigned char* __restrict__ txtQ,
    float* __restrict__ out)
{
    if (blockIdx.x == 0 && threadIdx.x == 0) *out = 0.0f;

    const int lane = threadIdx.x & 63;
    int w = blockIdx.x * 4 + (threadIdx.x >> 6);
    const float* src; unsigned char* dst;
    if (w < B_SZ) { src = img + (size_t)w * D_SZ; dst = imgQ + (size_t)w * D_SZ; }
    else { w -= B_SZ; src = txt + (size_t)w * D_SZ; dst = txtQ + (size_t)w * D_SZ; }

    float4 v[4];
    float ss = 0.0f;
    #pragma unroll
    for (int i = 0; i < 4; ++i) {
        v[i] = ((const float4*)src)[lane + 64 * i];
        ss += v[i].x*v[i].x + v[i].y*v[i].y + v[i].z*v[i].z + v[i].w*v[i].w;
    }
    #pragma unroll
    for (int off = 1; off < 64; off <<= 1) ss += __shfl_xor(ss, off, 64);
    const float scale = 1.0f / fmaxf(sqrtf(ss), 1e-12f);

    #pragma unroll
    for (int i = 0; i < 4; ++i) {
        int packed = 0;
        packed = __builtin_amdgcn_cvt_pk_fp8_f32(v[i].x * scale, v[i].y * scale, packed, false);
        packed = __builtin_amdgcn_cvt_pk_fp8_f32(v[i].z * scale, v[i].w * scale, packed, true);
        ((int*)dst)[lane + 64 * i] = packed;
    }
}

// Fused MX-fp8 GEMM (A @ B^T) + SigLIP loss. Block tile 256x256, 512 threads
// = 8 waves in 2(m)x4(n); wave tile 128x64 (8mt x 4nt of 16x16x128
// scaled-MFMA, scales = 1.0). BK=128 -> 8 K-iters.
//
// Rationale (R4 post-mortem): LDS-read traffic = (A-tile*wn_groups +
// B-tile*wm_groups) per kk. 256x256/8-wave cuts bytes/FLOP 25% vs 128x128
// (41 us vs 55 us LDS-pipe floor) and halves staging DMA. Register budget:
// acc 128 (AGPR) + ~120 VGPR <= 256 -> 2 waves/SIMD; LDS 128.5 KB -> 1
// block/CU either way, so spend the idle LDS on FULL double-buffering of
// both tiles: no stage-vs-read race, ONE barrier per K-iter, and the DMA
// for kk+1 has the whole iteration (frag reads + 32 MFMAs/wave) to land.
//
// LDS geometry per buffer: lo/hi 64-B-row arrays (R2's layout); granule at
// logical g stored at physical p = g ^ ((row>>1)&3); swizzle applied on the
// GLOBAL side of global_load_lds (LDS side stays wave-uniform base+lane*16).
__global__ __launch_bounds__(512, 2) void siglip_gemm_loss_fp8(
    const unsigned char* __restrict__ A,   // imgQ [B,D] e4m3
    const unsigned char* __restrict__ Bt,  // txtQ [B,D] e4m3
    const float* __restrict__ tp, const float* __restrict__ bp,
    float* __restrict__ out)
{
    __shared__ __align__(16) unsigned char As[2][2][256 * 64]; // [buf][lo/hi] 64 KB
    __shared__ __align__(16) unsigned char Bs[2][2][256 * 64]; // [buf][lo/hi] 64 KB

    const int tid  = threadIdx.x;
    const int lane = tid & 63;
    const int wave = tid >> 6;
    const int wm = wave & 1;        // 0..1 -> m-offset wm*128
    const int wn = wave >> 1;       // 0..3 -> n-offset wn*64
    const int bi = blockIdx.x * 256;
    const int bj = blockIdx.y * 256;
    const int quad = lane >> 4;     // 0..3 -> 32-byte K-chunk
    const int l16  = lane & 15;

    floatx4 acc[8][4];
    #pragma unroll
    for (int i = 0; i < 8; ++i)
        #pragma unroll
        for (int j = 0; j < 4; ++j)
            acc[i][j] = (floatx4){0.f, 0.f, 0.f, 0.f};

    // staging: 1024 slots per half-array; slot s -> row = s>>2, phys p = s&3,
    // global granule g = p ^ ((row>>1)&3). 512 thr x 2 its x 2 halves x 2 mats
    // = 8 glds16/thread per tile-pair.
    auto stage = [&](int k0, int buf) {
        #pragma unroll
        for (int it = 0; it < 2; ++it) {
            int s = tid + it * 512;
            int row = s >> 2, p = s & 3;
            int g = p ^ ((row >> 1) & 3);
            const unsigned char* ga = A  + ((size_t)(bi + row) * D_SZ + k0 + g * 16);
            const unsigned char* gb = Bt + ((size_t)(bj + row) * D_SZ + k0 + g * 16);
            glds16(ga,      As[buf][0] + s * 16);
            glds16(ga + 64, As[buf][1] + s * 16);
            glds16(gb,      Bs[buf][0] + s * 16);
            glds16(gb + 64, Bs[buf][1] + s * 16);
        }
    };

    // fragment read geometry (proven R2/R4): array = quad>>1, granule pair
    // (quad&1)*2 ^ sw (sw = (l16>>1)&3), physical positions p0, p0^1.
    const int sw   = (l16 >> 1) & 3;
    const int hsel = quad >> 1;
    const int p0   = ((quad & 1) * 2) ^ sw;
    const int p1   = p0 ^ 1;

    stage(0, 0);

    for (int kk = 0; kk < D_SZ / 128; ++kk) {
        const int buf = kk & 1;
        __syncthreads();   // own-DMA vmcnt drained by each wave before barrier
                           // => buf's tiles fully visible; buf^1 readers done.

        if (kk + 1 < D_SZ / 128)
            stage((kk + 1) * 128, buf ^ 1);  // lands anytime before next barrier

        int8v bfr[4];
        #pragma unroll
        for (int nt = 0; nt < 4; ++nt) {
            int r = wn * 64 + nt * 16 + l16;
            int4v lo = *(const int4v*)(Bs[buf][hsel] + r * 64 + p0 * 16);
            int4v hi = *(const int4v*)(Bs[buf][hsel] + r * 64 + p1 * 16);
            bfr[nt][0]=lo[0]; bfr[nt][1]=lo[1]; bfr[nt][2]=lo[2]; bfr[nt][3]=lo[3];
            bfr[nt][4]=hi[0]; bfr[nt][5]=hi[1]; bfr[nt][6]=hi[2]; bfr[nt][7]=hi[3];
        }

        #pragma unroll
        for (int mt = 0; mt < 8; ++mt) {
            int r = wm * 128 + mt * 16 + l16;
            int4v lo = *(const int4v*)(As[buf][hsel] + r * 64 + p0 * 16);
            int4v hi = *(const int4v*)(As[buf][hsel] + r * 64 + p1 * 16);
            int8v af;
            af[0]=lo[0]; af[1]=lo[1]; af[2]=lo[2]; af[3]=lo[3];
            af[4]=hi[0]; af[5]=hi[1]; af[6]=hi[2]; af[7]=hi[3];
            #pragma unroll
            for (int nt = 0; nt < 4; ++nt)
                acc[mt][nt] = __builtin_amdgcn_mfma_scale_f32_16x16x128_f8f6f4(
                    af, bfr[nt], acc[mt][nt],
                    0, 0,          // cbsz=fp8, blgp=fp8
                    0, 127,        // scale A: E8M0 127 = 1.0
                    0, 127);       // scale B
        }
    }

    // Epilogue: softplus(-label*logit) with hw exp/log, reduce.
    const float t    = fminf(__expf(tp[0]), 100.0f);
    const float bias = bp[0];
    float lsum = 0.0f;
    #pragma unroll
    for (int mt = 0; mt < 8; ++mt) {
        #pragma unroll
        for (int nt = 0; nt < 4; ++nt) {
            const int jj = bj + wn * 64 + nt * 16 + l16;               // C/D col
            #pragma unroll
            for (int r = 0; r < 4; ++r) {
                const int ii = bi + wm * 128 + mt * 16 + quad * 4 + r; // C/D row
                float logit = fmaf(acc[mt][nt][r], t, bias);
                float z = (ii == jj) ? logit : -logit;
                float e = __expf(-fabsf(z));
                lsum += fmaxf(-z, 0.0f) + __logf(1.0f + e);
            }
        }
    }
    #pragma unroll
    for (int off = 32; off > 0; off >>= 1) lsum += __shfl_down(lsum, off, 64);

    __shared__ float red[8];
    if (lane == 0) red[wave] = lsum;
    __syncthreads();
    if (tid == 0) {
        float s = 0.0f;
        #pragma unroll
        for (int i = 0; i < 8; ++i) s += red[i];
        atomicAdd(out, s * (1.0f / (float)B_SZ));
    }
}

extern "C" void kernel_launch(void* const* d_in, const int* in_sizes, int n_in,
                              void* d_out, int out_size, void* d_ws, size_t ws_size,
                              hipStream_t stream) {
    const float* img = (const float*)d_in[0];
    const float* txt = (const float*)d_in[1];
    const float* tp  = (const float*)d_in[2];
    const float* bp  = (const float*)d_in[3];
    float* out = (float*)d_out;

    unsigned char* imgQ = (unsigned char*)d_ws;                   // 8 MB
    unsigned char* txtQ = imgQ + (size_t)B_SZ * D_SZ;             // 8 MB

    norm_cast_fp8<<<(2 * B_SZ) / 4, 256, 0, stream>>>(img, txt, imgQ, txtQ, out);
    dim3 grid(B_SZ / 256, B_SZ / 256);
    siglip_gemm_loss_fp8<<<grid, 512, 0, stream>>>(imgQ, txtQ, tp, bp, out);
}